// Round 1
// 711.360 us; speedup vs baseline: 1.1301x; 1.1301x over previous
//
#include <hip/hip_runtime.h>

// Problem constants
#define NWIN 2048   // 2 * 32 * 32 windows
#define DIM 256
#define HEADS 8
#define HD 32
#define WA 64       // window area
#define N1 128      // query count
#define SCALE 0.17677669529663687f  // 32^-0.5

typedef _Float16 hvec8 __attribute__((ext_vector_type(8)));
typedef _Float16 hvec4 __attribute__((ext_vector_type(4)));
typedef float fvec4 __attribute__((ext_vector_type(4)));

// ---------------------------------------------------------------------------
// Prep: convert q (scaled), kv_w, proj_w to f16; materialize rel-pos bias fp32
// in MFMA-fragment order [h][p][l15][nt] so stage B loads one fvec4 per row.
// ---------------------------------------------------------------------------
__global__ void prep_kernel(const float* __restrict__ embeds,
                            const float* __restrict__ rpb,
                            const float* __restrict__ kvw,
                            const float* __restrict__ pjw,
                            _Float16* __restrict__ qh,
                            _Float16* __restrict__ kvwh,
                            _Float16* __restrict__ pjwh,
                            float* __restrict__ biasf) {
  int t = blockIdx.x * 256 + threadIdx.x;  // 0..131071
  kvwh[t] = (_Float16)kvw[t];              // [512][256] same layout
  if (t < 65536) pjwh[t] = (_Float16)pjw[t];  // [256][256]
  if (t < 32768) {
    // q: [h][n1][d] <- embeds[n1*256 + h*32 + d] * SCALE
    int h = t >> 12, n1 = (t >> 5) & 127, d = t & 31;
    qh[t] = (_Float16)(embeds[n1 * 256 + h * 32 + d] * SCALE);
    // bias element (h, p, kk) -> frag order: [h][p][kk&15][kk>>4]
    int p = (t >> 6) & 63, kk = t & 63;
    int ridx = ((p >> 3) - (kk >> 3) + 7) * 15 + ((p & 7) - (kk & 7) + 7);
    int idx = (t & ~63) | ((kk & 15) << 2) | (kk >> 4);
    biasf[idx] = rpb[ridx * 8 + h];
  }
}

// ---------------------------------------------------------------------------
// Fused: window KV-proj -> 8-head attention -> out proj. One block per window.
// 512 threads = 8 waves. Key changes vs previous version:
//  - x window staged into LDS as f16 ONCE (was: 8 waves each re-reading the
//    full 64KB fp32 window from global + 8x redundant converts)
//  - wave wv computes exactly head wv's K and V channels in stage A, so the
//    K/V reg->frag transpose is wave-private LDS (no cross-wave exchange)
//  - register pressure fits the 128-reg cap of __launch_bounds__(512,4):
//    no scratch spills (was ~560MB of spill write traffic)
// LDS regions (52224 B -> still 2 blk/CU, reg-capped):
//   stage A : Xs[64][264] f16 (33792 B)
//   exchange: per-wave scratch 8 x 5120 B (aliases Xs, after barrier)
//   stage BC: Os[64][264] (33792 B) | Pc 8 x [16][72] (18432 B)
// ---------------------------------------------------------------------------
__global__ __launch_bounds__(512, 4) void attn_kernel(
    const float* __restrict__ x,
    const float* __restrict__ kvb,
    const float* __restrict__ pjb,
    const _Float16* __restrict__ qh,
    const _Float16* __restrict__ kvwh,
    const _Float16* __restrict__ pjwh,
    const float* __restrict__ biasf,
    float* __restrict__ out) {

  __shared__ __align__(16) char smem[52224];
  _Float16* const Xs = (_Float16*)smem;            // [64][264] x window, f16
  _Float16* const Os = (_Float16*)smem;            // [64][264] attn out half

  const int tid = threadIdx.x;
  const int wv = tid >> 6;
  const int lane = tid & 63;
  const int l15 = lane & 15;
  const int l4 = lane >> 4;

  const int w = blockIdx.x;
  const int b = w >> 10, hb = (w >> 5) & 31, wb = w & 31;

  const fvec4 fz = {0.f, 0.f, 0.f, 0.f};

  // ======== Stage X: window -> LDS f16 (each element read/converted once) ===
  {
    const float* xw = x + ((((size_t)b * 256 + hb * 8) * 256) + wb * 8) * 256;
#pragma unroll
    for (int it = 0; it < 2; ++it) {
      int c = it * 512 + tid;            // chunk 0..1023: 16 floats each
      int row = c >> 4;                  // window row 0..63
      int ch0 = (c & 15) << 4;           // channel 0,16,..,240
      const float* src = xw + (((row >> 3) * 256 + (row & 7)) << 8) + ch0;
      fvec4 u0 = *(const fvec4*)(src);
      fvec4 u1 = *(const fvec4*)(src + 4);
      fvec4 u2 = *(const fvec4*)(src + 8);
      fvec4 u3 = *(const fvec4*)(src + 12);
      hvec8 h0, h1;
      h0[0] = (_Float16)u0[0]; h0[1] = (_Float16)u0[1];
      h0[2] = (_Float16)u0[2]; h0[3] = (_Float16)u0[3];
      h0[4] = (_Float16)u1[0]; h0[5] = (_Float16)u1[1];
      h0[6] = (_Float16)u1[2]; h0[7] = (_Float16)u1[3];
      h1[0] = (_Float16)u2[0]; h1[1] = (_Float16)u2[1];
      h1[2] = (_Float16)u2[2]; h1[3] = (_Float16)u2[3];
      h1[4] = (_Float16)u3[0]; h1[5] = (_Float16)u3[1];
      h1[6] = (_Float16)u3[2]; h1[7] = (_Float16)u3[3];
      *(hvec8*)&Xs[row * 264 + ch0] = h0;
      *(hvec8*)&Xs[row * 264 + ch0 + 8] = h1;
    }
  }
  __syncthreads();

  // ======== Stage A: wave wv computes head wv's K and V (64 channels) =======
  // K channels wv*32..+32 (nt 0..1), V channels 256+wv*32..+32 (nt 2..3)
  fvec4 acc[4][4];
#pragma unroll
  for (int mt = 0; mt < 4; ++mt)
#pragma unroll
    for (int nt = 0; nt < 4; ++nt) acc[mt][nt] = fz;
  {
    const _Float16* bK = kvwh + ((size_t)(wv * 32 + l15) << 8);
    const _Float16* bV = kvwh + ((size_t)(256 + wv * 32 + l15) << 8);
    for (int ks = 0; ks < 8; ++ks) {
      const int k0 = ks * 32 + l4 * 8;
      hvec8 af[4];
#pragma unroll
      for (int mt = 0; mt < 4; ++mt)
        af[mt] = *(const hvec8*)&Xs[(mt * 16 + l15) * 264 + k0];
      hvec8 bfg[4];
      bfg[0] = *(const hvec8*)(bK + k0);
      bfg[1] = *(const hvec8*)(bK + 16 * 256 + k0);
      bfg[2] = *(const hvec8*)(bV + k0);
      bfg[3] = *(const hvec8*)(bV + 16 * 256 + k0);
#pragma unroll
      for (int mt = 0; mt < 4; ++mt)
#pragma unroll
        for (int nt = 0; nt < 4; ++nt)
          acc[mt][nt] = __builtin_amdgcn_mfma_f32_16x16x32_f16(af[mt], bfg[nt], acc[mt][nt], 0, 0, 0);
    }
  }
  __syncthreads();  // Xs dead; per-wave scratch (aliased over Xs) usable

  // ======== Wave-private K/V transpose: regs -> LDS -> MFMA B-frags ========
  _Float16* const Sw = (_Float16*)(smem + wv * 5120);
  hvec8 kf[4];      // K B-frags: B[k=d][n=kk]
  hvec8 vf[2][2];   // V B-frags: B[k=kk][n=d]
  {
    // K natural [kk 0..63][d 0..31], row pad 40 (80B stride, 16B aligned)
#pragma unroll
    for (int nt = 0; nt < 2; ++nt) {
      const int d = nt * 16 + l15;
      const float bb = kvb[wv * 32 + d];
#pragma unroll
      for (int mt = 0; mt < 4; ++mt)
#pragma unroll
        for (int r = 0; r < 4; ++r)
          Sw[(mt * 16 + l4 * 4 + r) * 40 + d] = (_Float16)(acc[mt][nt][r] + bb);
    }
#pragma unroll
    for (int nt4 = 0; nt4 < 4; ++nt4)
      kf[nt4] = *(const hvec8*)&Sw[(nt4 * 16 + l15) * 40 + l4 * 8];
    // V transposed [d 0..31][kk 0..63], row pad 72 (144B stride, 16B aligned)
    // (same Sw region reused; within-wave DS ordering keeps this safe)
#pragma unroll
    for (int nt = 0; nt < 2; ++nt) {
      const int d = nt * 16 + l15;
      const float bb = kvb[256 + wv * 32 + d];
#pragma unroll
      for (int mt = 0; mt < 4; ++mt) {
        hvec4 pk;
#pragma unroll
        for (int r = 0; r < 4; ++r)
          pk[r] = (_Float16)(acc[mt][nt + 2][r] + bb);
        *(hvec4*)&Sw[d * 72 + mt * 16 + l4 * 4] = pk;
      }
    }
#pragma unroll
    for (int nv = 0; nv < 2; ++nv)
#pragma unroll
      for (int k2 = 0; k2 < 2; ++k2)
        vf[nv][k2] = *(const hvec8*)&Sw[(nv * 16 + l15) * 72 + k2 * 32 + l4 * 8];
  }
  __syncthreads();  // all waves' scratch reads done; LDS becomes Os/Pc

  const int h = wv;
  const float* bh = biasf + h * 4096;
  _Float16* const pc = (_Float16*)(smem + 33792 + wv * 2304);  // [16][72]

  for (int half = 0; half < 2; ++half) {
    // =============== Stage B half: attention rows [half*64, half*64+64) =====
    {
      hvec8 qf[4];
#pragma unroll
      for (int q4 = 0; q4 < 4; ++q4) {
        int mt = half * 4 + q4;
        qf[q4] = *(const hvec8*)(qh + (size_t)(h * 128 + mt * 16 + l15) * 32 + l4 * 8);
      }
      for (int q4 = 0; q4 < 4; ++q4) {
        const int mt = half * 4 + q4;
        fvec4 s[4];
#pragma unroll
        for (int nt = 0; nt < 4; ++nt)
          s[nt] = __builtin_amdgcn_mfma_f32_16x16x32_f16(qf[q4], kf[nt], fz, 0, 0, 0);
        // + relative position bias (rows tile mod 64), frag-order fvec4 loads
        const int pbase = (mt * 16 + l4 * 4) & 63;
#pragma unroll
        for (int r = 0; r < 4; ++r) {
          fvec4 bv = *(const fvec4*)&bh[(pbase + r) * 64 + l15 * 4];
#pragma unroll
          for (int nt = 0; nt < 4; ++nt) s[nt][r] += bv[nt];
        }
        // in-register softmax over kk (4 in-lane regs x 16 lanes)
#pragma unroll
        for (int r = 0; r < 4; ++r) {
          float mx = fmaxf(fmaxf(s[0][r], s[1][r]), fmaxf(s[2][r], s[3][r]));
          mx = fmaxf(mx, __shfl_xor(mx, 1));
          mx = fmaxf(mx, __shfl_xor(mx, 2));
          mx = fmaxf(mx, __shfl_xor(mx, 4));
          mx = fmaxf(mx, __shfl_xor(mx, 8));
          float sm = 0.f;
#pragma unroll
          for (int nt = 0; nt < 4; ++nt) {
            float e = __expf(s[nt][r] - mx);
            s[nt][r] = e;
            sm += e;
          }
          sm += __shfl_xor(sm, 1);
          sm += __shfl_xor(sm, 2);
          sm += __shfl_xor(sm, 4);
          sm += __shfl_xor(sm, 8);
          const float iv = 1.0f / sm;
#pragma unroll
          for (int nt = 0; nt < 4; ++nt) s[nt][r] *= iv;
        }
        // P chunk -> wave-private LDS (DS ops in-order within a wave)
#pragma unroll
        for (int nt = 0; nt < 4; ++nt)
#pragma unroll
          for (int r = 0; r < 4; ++r)
            pc[(l4 * 4 + r) * 72 + nt * 16 + l15] = (_Float16)s[nt][r];
        // P A-frags: A[m=q][k=kk]
        hvec8 pf[2];
#pragma unroll
        for (int k2 = 0; k2 < 2; ++k2)
          pf[k2] = *(const hvec8*)&pc[l15 * 72 + k2 * 32 + l4 * 8];
        fvec4 o[2];
#pragma unroll
        for (int nv = 0; nv < 2; ++nv) {
          o[nv] = __builtin_amdgcn_mfma_f32_16x16x32_f16(pf[0], vf[nv][0], fz, 0, 0, 0);
          o[nv] = __builtin_amdgcn_mfma_f32_16x16x32_f16(pf[1], vf[nv][1], o[nv], 0, 0, 0);
        }
#pragma unroll
        for (int nv = 0; nv < 2; ++nv)
#pragma unroll
          for (int r = 0; r < 4; ++r) {
            int row = q4 * 16 + l4 * 4 + r;          // local row in half
            int col = h * 32 + nv * 16 + l15;
            Os[row * 264 + col] = (_Float16)o[nv][r];
          }
      }
    }
    __syncthreads();

    // =============== Stage C half: out rows = Os[64][256] @ proj_w^T + b ====
    {
      const int c0 = wv * 32;  // out-channel slice per wave
      fvec4 po[4][2];
#pragma unroll
      for (int q4 = 0; q4 < 4; ++q4)
#pragma unroll
        for (int nb = 0; nb < 2; ++nb) po[q4][nb] = fz;

      for (int ks = 0; ks < 8; ++ks) {
        const int k0 = ks * 32 + l4 * 8;
        hvec8 am[4];
#pragma unroll
        for (int q4 = 0; q4 < 4; ++q4)
          am[q4] = *(const hvec8*)&Os[(q4 * 16 + l15) * 264 + k0];
        hvec8 bn[2];
#pragma unroll
        for (int nb = 0; nb < 2; ++nb)
          bn[nb] = *(const hvec8*)(pjwh + (size_t)(c0 + nb * 16 + l15) * 256 + k0);
#pragma unroll
        for (int q4 = 0; q4 < 4; ++q4)
#pragma unroll
          for (int nb = 0; nb < 2; ++nb)
            po[q4][nb] = __builtin_amdgcn_mfma_f32_16x16x32_f16(am[q4], bn[nb], po[q4][nb], 0, 0, 0);
      }
      float pb[2];
#pragma unroll
      for (int nb = 0; nb < 2; ++nb) pb[nb] = pjb[c0 + nb * 16 + l15];
      float* ow = out + (size_t)w * (N1 * DIM) + (size_t)half * 64 * DIM;
#pragma unroll
      for (int q4 = 0; q4 < 4; ++q4)
#pragma unroll
        for (int nb = 0; nb < 2; ++nb)
#pragma unroll
          for (int r = 0; r < 4; ++r) {
            int row = q4 * 16 + l4 * 4 + r;
            int col = c0 + nb * 16 + l15;
            ow[row * 256 + col] = po[q4][nb][r] + pb[nb];
          }
    }
    if (half == 0) __syncthreads();   // B2 rewrites Os after C1 reads
  }
}

// ---------------------------------------------------------------------------
extern "C" void kernel_launch(void* const* d_in, const int* in_sizes, int n_in,
                              void* d_out, int out_size, void* d_ws, size_t ws_size,
                              hipStream_t stream) {
  (void)in_sizes; (void)n_in; (void)out_size; (void)ws_size;
  const float* embeds = (const float*)d_in[0];  // [1,128,256]
  const float* x      = (const float*)d_in[1];  // [2,256,256,256]
  const float* rpb    = (const float*)d_in[2];  // [225,8]
  const float* kvw    = (const float*)d_in[3];  // [512,256]
  const float* kvb    = (const float*)d_in[4];  // [512]
  const float* pjw    = (const float*)d_in[5];  // [256,256]
  const float* pjb    = (const float*)d_in[6];  // [256]
  float* out = (float*)d_out;                   // [2048,128,256]

  char* ws = (char*)d_ws;                       // 576 KB used
  _Float16* qh    = (_Float16*)(ws);            // 65536 B  : q f16 [8][128][32]
  _Float16* kvwh  = (_Float16*)(ws + 65536);    // 262144 B : kv_w f16
  _Float16* pjwh  = (_Float16*)(ws + 327680);   // 131072 B : proj_w f16
  float*    biasf = (float*)(ws + 458752);      // 131072 B : bias fp32 frag-order

  prep_kernel<<<512, 256, 0, stream>>>(embeds, rpb, kvw, pjw, qh, kvwh, pjwh, biasf);
  attn_kernel<<<NWIN, 512, 0, stream>>>(x, kvb, pjb, qh, kvwh, pjwh, biasf, out);
}

// Round 2
// 652.217 us; speedup vs baseline: 1.2325x; 1.0907x over previous
//
#include <hip/hip_runtime.h>

// Problem constants
#define NWIN 2048   // 2 * 32 * 32 windows
#define DIM 256
#define HEADS 8
#define HD 32
#define WA 64       // window area
#define N1 128      // query count
#define SCALE 0.17677669529663687f  // 32^-0.5

typedef _Float16 hvec8 __attribute__((ext_vector_type(8)));
typedef _Float16 hvec4 __attribute__((ext_vector_type(4)));
typedef float fvec4 __attribute__((ext_vector_type(4)));

// ---------------------------------------------------------------------------
// Prep: convert q (scaled), kv_w, proj_w to f16; materialize rel-pos bias fp32
// in MFMA-fragment order [h][p][l15][nt] so stage B loads one fvec4 per row.
// ---------------------------------------------------------------------------
__global__ void prep_kernel(const float* __restrict__ embeds,
                            const float* __restrict__ rpb,
                            const float* __restrict__ kvw,
                            const float* __restrict__ pjw,
                            _Float16* __restrict__ qh,
                            _Float16* __restrict__ kvwh,
                            _Float16* __restrict__ pjwh,
                            float* __restrict__ biasf) {
  int t = blockIdx.x * 256 + threadIdx.x;  // 0..131071
  kvwh[t] = (_Float16)kvw[t];              // [512][256] same layout
  if (t < 65536) pjwh[t] = (_Float16)pjw[t];  // [256][256]
  if (t < 32768) {
    // q: [h][n1][d] <- embeds[n1*256 + h*32 + d] * SCALE
    int h = t >> 12, n1 = (t >> 5) & 127, d = t & 31;
    qh[t] = (_Float16)(embeds[n1 * 256 + h * 32 + d] * SCALE);
    // bias element (h, p, kk) -> frag order: [h][p][kk&15][kk>>4]
    int p = (t >> 6) & 63, kk = t & 63;
    int ridx = ((p >> 3) - (kk >> 3) + 7) * 15 + ((p & 7) - (kk & 7) + 7);
    int idx = (t & ~63) | ((kk & 15) << 2) | (kk >> 4);
    biasf[idx] = rpb[ridx * 8 + h];
  }
}

// ---------------------------------------------------------------------------
// Fused: window KV-proj -> 8-head attention -> out proj. One block per window.
// 512 threads = 8 waves. Changes vs previous version (anti-spill round):
//  - stage A split into K-pass then V-pass: acc[4][2] (32 AGPR) not [4][4] (64)
//  - per-wave transpose scratch Sw is a DEDICATED LDS region (doesn't alias
//    Xs), so each pass can bounce its result while Xs stays live
//  - single-use MFMA fragments (af/qf/am) loaded inside consuming loop
//  => peak regs ~105 of the 128 cap of __launch_bounds__(512,4): no scratch
// LDS map (74752 B -> 2 blk/CU):
//   [0,33792)        Xs[64][264] f16   (stage A)   | Os[64][264] (stage B/C)
//   [33792,74752)    Sw per-wave 8x5120 (stage A)  | Pc 8x[16][72] at 33792+
// ---------------------------------------------------------------------------
__global__ __launch_bounds__(512, 4) void attn_kernel(
    const float* __restrict__ x,
    const float* __restrict__ kvb,
    const float* __restrict__ pjb,
    const _Float16* __restrict__ qh,
    const _Float16* __restrict__ kvwh,
    const _Float16* __restrict__ pjwh,
    const float* __restrict__ biasf,
    float* __restrict__ out) {

  __shared__ __align__(16) char smem[74752];
  _Float16* const Xs = (_Float16*)smem;            // [64][264] x window, f16
  _Float16* const Os = (_Float16*)smem;            // [64][264] attn out half

  const int tid = threadIdx.x;
  const int wv = tid >> 6;
  const int lane = tid & 63;
  const int l15 = lane & 15;
  const int l4 = lane >> 4;

  const int w = blockIdx.x;
  const int b = w >> 10, hb = (w >> 5) & 31, wb = w & 31;

  const fvec4 fz = {0.f, 0.f, 0.f, 0.f};

  // ======== Stage X: window -> LDS f16 (each element read/converted once) ===
  {
    const float* xw = x + ((((size_t)b * 256 + hb * 8) * 256) + wb * 8) * 256;
#pragma unroll
    for (int it = 0; it < 2; ++it) {
      int c = it * 512 + tid;            // chunk 0..1023: 16 floats each
      int row = c >> 4;                  // window row 0..63
      int ch0 = (c & 15) << 4;           // channel 0,16,..,240
      const float* src = xw + (((row >> 3) * 256 + (row & 7)) << 8) + ch0;
      fvec4 u0 = *(const fvec4*)(src);
      fvec4 u1 = *(const fvec4*)(src + 4);
      fvec4 u2 = *(const fvec4*)(src + 8);
      fvec4 u3 = *(const fvec4*)(src + 12);
      hvec8 h0, h1;
      h0[0] = (_Float16)u0[0]; h0[1] = (_Float16)u0[1];
      h0[2] = (_Float16)u0[2]; h0[3] = (_Float16)u0[3];
      h0[4] = (_Float16)u1[0]; h0[5] = (_Float16)u1[1];
      h0[6] = (_Float16)u1[2]; h0[7] = (_Float16)u1[3];
      h1[0] = (_Float16)u2[0]; h1[1] = (_Float16)u2[1];
      h1[2] = (_Float16)u2[2]; h1[3] = (_Float16)u2[3];
      h1[4] = (_Float16)u3[0]; h1[5] = (_Float16)u3[1];
      h1[6] = (_Float16)u3[2]; h1[7] = (_Float16)u3[3];
      *(hvec8*)&Xs[row * 264 + ch0] = h0;
      *(hvec8*)&Xs[row * 264 + ch0 + 8] = h1;
    }
  }
  __syncthreads();

  // ======== Stage A: wave wv computes head wv's K then V (2 passes) ========
  // Sw: dedicated per-wave scratch; K natural [64][40], then V^T [32][72]
  _Float16* const Sw = (_Float16*)(smem + 33792 + wv * 5120);
  hvec8 kf[4];      // K B-frags: B[k=d][n=kk]   (persistent)
  hvec8 vf[2][2];   // V B-frags: B[k=kk][n=d]   (persistent)
  {
    fvec4 acc[4][2];
    // ---- K pass: channels wv*32 .. +32 ----
#pragma unroll
    for (int mt = 0; mt < 4; ++mt)
#pragma unroll
      for (int nt = 0; nt < 2; ++nt) acc[mt][nt] = fz;
    {
      const _Float16* bK = kvwh + ((size_t)(wv * 32 + l15) << 8);
      for (int ks = 0; ks < 8; ++ks) {
        const int k0 = ks * 32 + l4 * 8;
        hvec8 b0 = *(const hvec8*)(bK + k0);
        hvec8 b1 = *(const hvec8*)(bK + 16 * 256 + k0);
#pragma unroll
        for (int mt = 0; mt < 4; ++mt) {
          hvec8 a = *(const hvec8*)&Xs[(mt * 16 + l15) * 264 + k0];
          acc[mt][0] = __builtin_amdgcn_mfma_f32_16x16x32_f16(a, b0, acc[mt][0], 0, 0, 0);
          acc[mt][1] = __builtin_amdgcn_mfma_f32_16x16x32_f16(a, b1, acc[mt][1], 0, 0, 0);
        }
      }
    }
    // K epilogue: +bias, natural [kk][d] (pad 40), then load kf frags
#pragma unroll
    for (int nt = 0; nt < 2; ++nt) {
      const int d = nt * 16 + l15;
      const float bb = kvb[wv * 32 + d];
#pragma unroll
      for (int mt = 0; mt < 4; ++mt)
#pragma unroll
        for (int r = 0; r < 4; ++r)
          Sw[(mt * 16 + l4 * 4 + r) * 40 + d] = (_Float16)(acc[mt][nt][r] + bb);
    }
#pragma unroll
    for (int nt4 = 0; nt4 < 4; ++nt4)
      kf[nt4] = *(const hvec8*)&Sw[(nt4 * 16 + l15) * 40 + l4 * 8];

    // ---- V pass: channels 256 + wv*32 .. +32 ----
#pragma unroll
    for (int mt = 0; mt < 4; ++mt)
#pragma unroll
      for (int nt = 0; nt < 2; ++nt) acc[mt][nt] = fz;
    {
      const _Float16* bV = kvwh + ((size_t)(256 + wv * 32 + l15) << 8);
      for (int ks = 0; ks < 8; ++ks) {
        const int k0 = ks * 32 + l4 * 8;
        hvec8 b0 = *(const hvec8*)(bV + k0);
        hvec8 b1 = *(const hvec8*)(bV + 16 * 256 + k0);
#pragma unroll
        for (int mt = 0; mt < 4; ++mt) {
          hvec8 a = *(const hvec8*)&Xs[(mt * 16 + l15) * 264 + k0];
          acc[mt][0] = __builtin_amdgcn_mfma_f32_16x16x32_f16(a, b0, acc[mt][0], 0, 0, 0);
          acc[mt][1] = __builtin_amdgcn_mfma_f32_16x16x32_f16(a, b1, acc[mt][1], 0, 0, 0);
        }
      }
    }
    // V epilogue: +bias, transposed [d][kk] (pad 72, hvec4 packed), load vf
    // (Sw reuse after kf loads is safe: DS ops are in-order within a wave)
#pragma unroll
    for (int nt = 0; nt < 2; ++nt) {
      const int d = nt * 16 + l15;
      const float bb = kvb[256 + wv * 32 + d];
#pragma unroll
      for (int mt = 0; mt < 4; ++mt) {
        hvec4 pk;
#pragma unroll
        for (int r = 0; r < 4; ++r)
          pk[r] = (_Float16)(acc[mt][nt][r] + bb);
        *(hvec4*)&Sw[d * 72 + mt * 16 + l4 * 4] = pk;
      }
    }
#pragma unroll
    for (int nv = 0; nv < 2; ++nv)
#pragma unroll
      for (int k2 = 0; k2 < 2; ++k2)
        vf[nv][k2] = *(const hvec8*)&Sw[(nv * 16 + l15) * 72 + k2 * 32 + l4 * 8];
  }
  __syncthreads();  // Xs/Sw dead everywhere; LDS becomes Os/Pc

  const int h = wv;
  const float* bh = biasf + h * 4096;
  _Float16* const pc = (_Float16*)(smem + 33792 + wv * 2304);  // [16][72]

  for (int half = 0; half < 2; ++half) {
    // =============== Stage B half: attention rows [half*64, half*64+64) =====
    {
      for (int q4 = 0; q4 < 4; ++q4) {
        const int mt = half * 4 + q4;
        hvec8 qf = *(const hvec8*)(qh + (size_t)(h * 128 + mt * 16 + l15) * 32 + l4 * 8);
        fvec4 s[4];
#pragma unroll
        for (int nt = 0; nt < 4; ++nt)
          s[nt] = __builtin_amdgcn_mfma_f32_16x16x32_f16(qf, kf[nt], fz, 0, 0, 0);
        // + relative position bias (rows tile mod 64), frag-order fvec4 loads
        const int pbase = (mt * 16 + l4 * 4) & 63;
#pragma unroll
        for (int r = 0; r < 4; ++r) {
          fvec4 bv = *(const fvec4*)&bh[(pbase + r) * 64 + l15 * 4];
#pragma unroll
          for (int nt = 0; nt < 4; ++nt) s[nt][r] += bv[nt];
        }
        // in-register softmax over kk (4 in-lane regs x 16 lanes)
#pragma unroll
        for (int r = 0; r < 4; ++r) {
          float mx = fmaxf(fmaxf(s[0][r], s[1][r]), fmaxf(s[2][r], s[3][r]));
          mx = fmaxf(mx, __shfl_xor(mx, 1));
          mx = fmaxf(mx, __shfl_xor(mx, 2));
          mx = fmaxf(mx, __shfl_xor(mx, 4));
          mx = fmaxf(mx, __shfl_xor(mx, 8));
          float sm = 0.f;
#pragma unroll
          for (int nt = 0; nt < 4; ++nt) {
            float e = __expf(s[nt][r] - mx);
            s[nt][r] = e;
            sm += e;
          }
          sm += __shfl_xor(sm, 1);
          sm += __shfl_xor(sm, 2);
          sm += __shfl_xor(sm, 4);
          sm += __shfl_xor(sm, 8);
          const float iv = 1.0f / sm;
#pragma unroll
          for (int nt = 0; nt < 4; ++nt) s[nt][r] *= iv;
        }
        // P chunk -> wave-private LDS (DS ops in-order within a wave)
#pragma unroll
        for (int nt = 0; nt < 4; ++nt)
#pragma unroll
          for (int r = 0; r < 4; ++r)
            pc[(l4 * 4 + r) * 72 + nt * 16 + l15] = (_Float16)s[nt][r];
        // P A-frags: A[m=q][k=kk]
        hvec8 pf[2];
#pragma unroll
        for (int k2 = 0; k2 < 2; ++k2)
          pf[k2] = *(const hvec8*)&pc[l15 * 72 + k2 * 32 + l4 * 8];
        fvec4 o[2];
#pragma unroll
        for (int nv = 0; nv < 2; ++nv) {
          o[nv] = __builtin_amdgcn_mfma_f32_16x16x32_f16(pf[0], vf[nv][0], fz, 0, 0, 0);
          o[nv] = __builtin_amdgcn_mfma_f32_16x16x32_f16(pf[1], vf[nv][1], o[nv], 0, 0, 0);
        }
#pragma unroll
        for (int nv = 0; nv < 2; ++nv)
#pragma unroll
          for (int r = 0; r < 4; ++r) {
            int row = q4 * 16 + l4 * 4 + r;          // local row in half
            int col = h * 32 + nv * 16 + l15;
            Os[row * 264 + col] = (_Float16)o[nv][r];
          }
      }
    }
    __syncthreads();

    // =============== Stage C half: out rows = Os[64][256] @ proj_w^T + b ====
    {
      const int c0 = wv * 32;  // out-channel slice per wave
      fvec4 po[4][2];
#pragma unroll
      for (int q4 = 0; q4 < 4; ++q4)
#pragma unroll
        for (int nb = 0; nb < 2; ++nb) po[q4][nb] = fz;

      {
        const _Float16* bP = pjwh + ((size_t)(c0 + l15) << 8);
        for (int ks = 0; ks < 8; ++ks) {
          const int k0 = ks * 32 + l4 * 8;
          hvec8 bn0 = *(const hvec8*)(bP + k0);
          hvec8 bn1 = *(const hvec8*)(bP + 16 * 256 + k0);
#pragma unroll
          for (int q4 = 0; q4 < 4; ++q4) {
            hvec8 am = *(const hvec8*)&Os[(q4 * 16 + l15) * 264 + k0];
            po[q4][0] = __builtin_amdgcn_mfma_f32_16x16x32_f16(am, bn0, po[q4][0], 0, 0, 0);
            po[q4][1] = __builtin_amdgcn_mfma_f32_16x16x32_f16(am, bn1, po[q4][1], 0, 0, 0);
          }
        }
      }
      float pb[2];
#pragma unroll
      for (int nb = 0; nb < 2; ++nb) pb[nb] = pjb[c0 + nb * 16 + l15];
      float* ow = out + (size_t)w * (N1 * DIM) + (size_t)half * 64 * DIM;
#pragma unroll
      for (int q4 = 0; q4 < 4; ++q4)
#pragma unroll
        for (int nb = 0; nb < 2; ++nb)
#pragma unroll
          for (int r = 0; r < 4; ++r) {
            int row = q4 * 16 + l4 * 4 + r;
            int col = c0 + nb * 16 + l15;
            ow[row * 256 + col] = po[q4][nb][r] + pb[nb];
          }
    }
    if (half == 0) __syncthreads();   // B2 rewrites Os after C1 reads
  }
}

// ---------------------------------------------------------------------------
extern "C" void kernel_launch(void* const* d_in, const int* in_sizes, int n_in,
                              void* d_out, int out_size, void* d_ws, size_t ws_size,
                              hipStream_t stream) {
  (void)in_sizes; (void)n_in; (void)out_size; (void)ws_size;
  const float* embeds = (const float*)d_in[0];  // [1,128,256]
  const float* x      = (const float*)d_in[1];  // [2,256,256,256]
  const float* rpb    = (const float*)d_in[2];  // [225,8]
  const float* kvw    = (const float*)d_in[3];  // [512,256]
  const float* kvb    = (const float*)d_in[4];  // [512]
  const float* pjw    = (const float*)d_in[5];  // [256,256]
  const float* pjb    = (const float*)d_in[6];  // [256]
  float* out = (float*)d_out;                   // [2048,128,256]

  char* ws = (char*)d_ws;                       // 576 KB used
  _Float16* qh    = (_Float16*)(ws);            // 65536 B  : q f16 [8][128][32]
  _Float16* kvwh  = (_Float16*)(ws + 65536);    // 262144 B : kv_w f16
  _Float16* pjwh  = (_Float16*)(ws + 327680);   // 131072 B : proj_w f16
  float*    biasf = (float*)(ws + 458752);      // 131072 B : bias fp32 frag-order

  prep_kernel<<<512, 256, 0, stream>>>(embeds, rpb, kvw, pjw, qh, kvwh, pjwh, biasf);
  attn_kernel<<<NWIN, 512, 0, stream>>>(x, kvb, pjb, qh, kvwh, pjwh, biasf, out);
}

// Round 3
// 567.391 us; speedup vs baseline: 1.4168x; 1.1495x over previous
//
#include <hip/hip_runtime.h>

// Problem constants
#define NWIN 2048   // 2 * 32 * 32 windows
#define DIM 256
#define HEADS 8
#define HD 32
#define WA 64       // window area
#define N1 128      // query count
#define SCALE 0.17677669529663687f  // 32^-0.5

typedef _Float16 hvec8 __attribute__((ext_vector_type(8)));
typedef _Float16 hvec4 __attribute__((ext_vector_type(4)));
typedef float fvec4 __attribute__((ext_vector_type(4)));

// ---------------------------------------------------------------------------
// Prep: convert q (scaled), kv_w, proj_w to f16; materialize rel-pos bias fp32
// in MFMA-fragment order [h][p][l15][nt] so stage B loads one fvec4 per row.
// ---------------------------------------------------------------------------
__global__ void prep_kernel(const float* __restrict__ embeds,
                            const float* __restrict__ rpb,
                            const float* __restrict__ kvw,
                            const float* __restrict__ pjw,
                            _Float16* __restrict__ qh,
                            _Float16* __restrict__ kvwh,
                            _Float16* __restrict__ pjwh,
                            float* __restrict__ biasf) {
  int t = blockIdx.x * 256 + threadIdx.x;  // 0..131071
  kvwh[t] = (_Float16)kvw[t];              // [512][256] same layout
  if (t < 65536) pjwh[t] = (_Float16)pjw[t];  // [256][256]
  if (t < 32768) {
    // q: [h][n1][d] <- embeds[n1*256 + h*32 + d] * SCALE
    int h = t >> 12, n1 = (t >> 5) & 127, d = t & 31;
    qh[t] = (_Float16)(embeds[n1 * 256 + h * 32 + d] * SCALE);
    // bias element (h, p, kk) -> frag order: [h][p][kk&15][kk>>4]
    int p = (t >> 6) & 63, kk = t & 63;
    int ridx = ((p >> 3) - (kk >> 3) + 7) * 15 + ((p & 7) - (kk & 7) + 7);
    int idx = (t & ~63) | ((kk & 15) << 2) | (kk >> 4);
    biasf[idx] = rpb[ridx * 8 + h];
  }
}

// ---------------------------------------------------------------------------
// Fused: window KV-proj -> 8-head attention -> out proj. One block per window.
// 512 threads = 8 waves. Changes vs previous version (anti-spill round 2):
//  - __launch_bounds__(512, 2): min-wave floor relaxed so the register
//    allocator can use up to 256 unified regs/lane instead of spilling to
//    scratch to satisfy a 128-reg cap (round-2 counters: ~500 MB matched
//    excess in WRITE+FETCH = spill round-trips). If actual allocation lands
//    <=128 the HW still achieves 4 waves/SIMD; LDS permits 2 blk/CU.
//  - non-temporal loads for the x window (read-once) and non-temporal stores
//    for out (write-once): evict-first in L2, keeping the 576 KB weight
//    working set (kvwh/pjwh/qh/biasf) resident per XCD.
// LDS map (74752 B -> 2 blk/CU):
//   [0,33792)        Xs[64][264] f16   (stage A)   | Os[64][264] (stage B/C)
//   [33792,74752)    Sw per-wave 8x5120 (stage A)  | Pc 8x[16][72] at 33792+
// ---------------------------------------------------------------------------
__global__ __launch_bounds__(512, 2) void attn_kernel(
    const float* __restrict__ x,
    const float* __restrict__ kvb,
    const float* __restrict__ pjb,
    const _Float16* __restrict__ qh,
    const _Float16* __restrict__ kvwh,
    const _Float16* __restrict__ pjwh,
    const float* __restrict__ biasf,
    float* __restrict__ out) {

  __shared__ __align__(16) char smem[74752];
  _Float16* const Xs = (_Float16*)smem;            // [64][264] x window, f16
  _Float16* const Os = (_Float16*)smem;            // [64][264] attn out half

  const int tid = threadIdx.x;
  const int wv = tid >> 6;
  const int lane = tid & 63;
  const int l15 = lane & 15;
  const int l4 = lane >> 4;

  const int w = blockIdx.x;
  const int b = w >> 10, hb = (w >> 5) & 31, wb = w & 31;

  const fvec4 fz = {0.f, 0.f, 0.f, 0.f};

  // ======== Stage X: window -> LDS f16 (each element read/converted once) ===
  {
    const float* xw = x + ((((size_t)b * 256 + hb * 8) * 256) + wb * 8) * 256;
#pragma unroll
    for (int it = 0; it < 2; ++it) {
      int c = it * 512 + tid;            // chunk 0..1023: 16 floats each
      int row = c >> 4;                  // window row 0..63
      int ch0 = (c & 15) << 4;           // channel 0,16,..,240
      const float* src = xw + (((row >> 3) * 256 + (row & 7)) << 8) + ch0;
      fvec4 u0 = __builtin_nontemporal_load((const fvec4*)(src));
      fvec4 u1 = __builtin_nontemporal_load((const fvec4*)(src + 4));
      fvec4 u2 = __builtin_nontemporal_load((const fvec4*)(src + 8));
      fvec4 u3 = __builtin_nontemporal_load((const fvec4*)(src + 12));
      hvec8 h0, h1;
      h0[0] = (_Float16)u0[0]; h0[1] = (_Float16)u0[1];
      h0[2] = (_Float16)u0[2]; h0[3] = (_Float16)u0[3];
      h0[4] = (_Float16)u1[0]; h0[5] = (_Float16)u1[1];
      h0[6] = (_Float16)u1[2]; h0[7] = (_Float16)u1[3];
      h1[0] = (_Float16)u2[0]; h1[1] = (_Float16)u2[1];
      h1[2] = (_Float16)u2[2]; h1[3] = (_Float16)u2[3];
      h1[4] = (_Float16)u3[0]; h1[5] = (_Float16)u3[1];
      h1[6] = (_Float16)u3[2]; h1[7] = (_Float16)u3[3];
      *(hvec8*)&Xs[row * 264 + ch0] = h0;
      *(hvec8*)&Xs[row * 264 + ch0 + 8] = h1;
    }
  }
  __syncthreads();

  // ======== Stage A: wave wv computes head wv's K then V (2 passes) ========
  // Sw: dedicated per-wave scratch; K natural [64][40], then V^T [32][72]
  _Float16* const Sw = (_Float16*)(smem + 33792 + wv * 5120);
  hvec8 kf[4];      // K B-frags: B[k=d][n=kk]   (persistent)
  hvec8 vf[2][2];   // V B-frags: B[k=kk][n=d]   (persistent)
  {
    fvec4 acc[4][2];
    // ---- K pass: channels wv*32 .. +32 ----
#pragma unroll
    for (int mt = 0; mt < 4; ++mt)
#pragma unroll
      for (int nt = 0; nt < 2; ++nt) acc[mt][nt] = fz;
    {
      const _Float16* bK = kvwh + ((size_t)(wv * 32 + l15) << 8);
      for (int ks = 0; ks < 8; ++ks) {
        const int k0 = ks * 32 + l4 * 8;
        hvec8 b0 = *(const hvec8*)(bK + k0);
        hvec8 b1 = *(const hvec8*)(bK + 16 * 256 + k0);
#pragma unroll
        for (int mt = 0; mt < 4; ++mt) {
          hvec8 a = *(const hvec8*)&Xs[(mt * 16 + l15) * 264 + k0];
          acc[mt][0] = __builtin_amdgcn_mfma_f32_16x16x32_f16(a, b0, acc[mt][0], 0, 0, 0);
          acc[mt][1] = __builtin_amdgcn_mfma_f32_16x16x32_f16(a, b1, acc[mt][1], 0, 0, 0);
        }
      }
    }
    // K epilogue: +bias, natural [kk][d] (pad 40), then load kf frags
#pragma unroll
    for (int nt = 0; nt < 2; ++nt) {
      const int d = nt * 16 + l15;
      const float bb = kvb[wv * 32 + d];
#pragma unroll
      for (int mt = 0; mt < 4; ++mt)
#pragma unroll
        for (int r = 0; r < 4; ++r)
          Sw[(mt * 16 + l4 * 4 + r) * 40 + d] = (_Float16)(acc[mt][nt][r] + bb);
    }
#pragma unroll
    for (int nt4 = 0; nt4 < 4; ++nt4)
      kf[nt4] = *(const hvec8*)&Sw[(nt4 * 16 + l15) * 40 + l4 * 8];

    // ---- V pass: channels 256 + wv*32 .. +32 ----
#pragma unroll
    for (int mt = 0; mt < 4; ++mt)
#pragma unroll
      for (int nt = 0; nt < 2; ++nt) acc[mt][nt] = fz;
    {
      const _Float16* bV = kvwh + ((size_t)(256 + wv * 32 + l15) << 8);
      for (int ks = 0; ks < 8; ++ks) {
        const int k0 = ks * 32 + l4 * 8;
        hvec8 b0 = *(const hvec8*)(bV + k0);
        hvec8 b1 = *(const hvec8*)(bV + 16 * 256 + k0);
#pragma unroll
        for (int mt = 0; mt < 4; ++mt) {
          hvec8 a = *(const hvec8*)&Xs[(mt * 16 + l15) * 264 + k0];
          acc[mt][0] = __builtin_amdgcn_mfma_f32_16x16x32_f16(a, b0, acc[mt][0], 0, 0, 0);
          acc[mt][1] = __builtin_amdgcn_mfma_f32_16x16x32_f16(a, b1, acc[mt][1], 0, 0, 0);
        }
      }
    }
    // V epilogue: +bias, transposed [d][kk] (pad 72, hvec4 packed), load vf
    // (Sw reuse after kf loads is safe: DS ops are in-order within a wave)
#pragma unroll
    for (int nt = 0; nt < 2; ++nt) {
      const int d = nt * 16 + l15;
      const float bb = kvb[256 + wv * 32 + d];
#pragma unroll
      for (int mt = 0; mt < 4; ++mt) {
        hvec4 pk;
#pragma unroll
        for (int r = 0; r < 4; ++r)
          pk[r] = (_Float16)(acc[mt][nt][r] + bb);
        *(hvec4*)&Sw[d * 72 + mt * 16 + l4 * 4] = pk;
      }
    }
#pragma unroll
    for (int nv = 0; nv < 2; ++nv)
#pragma unroll
      for (int k2 = 0; k2 < 2; ++k2)
        vf[nv][k2] = *(const hvec8*)&Sw[(nv * 16 + l15) * 72 + k2 * 32 + l4 * 8];
  }
  __syncthreads();  // Xs/Sw dead everywhere; LDS becomes Os/Pc

  const int h = wv;
  const float* bh = biasf + h * 4096;
  _Float16* const pc = (_Float16*)(smem + 33792 + wv * 2304);  // [16][72]

  for (int half = 0; half < 2; ++half) {
    // =============== Stage B half: attention rows [half*64, half*64+64) =====
    {
      for (int q4 = 0; q4 < 4; ++q4) {
        const int mt = half * 4 + q4;
        hvec8 qf = *(const hvec8*)(qh + (size_t)(h * 128 + mt * 16 + l15) * 32 + l4 * 8);
        fvec4 s[4];
#pragma unroll
        for (int nt = 0; nt < 4; ++nt)
          s[nt] = __builtin_amdgcn_mfma_f32_16x16x32_f16(qf, kf[nt], fz, 0, 0, 0);
        // + relative position bias (rows tile mod 64), frag-order fvec4 loads
        const int pbase = (mt * 16 + l4 * 4) & 63;
#pragma unroll
        for (int r = 0; r < 4; ++r) {
          fvec4 bv = *(const fvec4*)&bh[(pbase + r) * 64 + l15 * 4];
#pragma unroll
          for (int nt = 0; nt < 4; ++nt) s[nt][r] += bv[nt];
        }
        // in-register softmax over kk (4 in-lane regs x 16 lanes)
#pragma unroll
        for (int r = 0; r < 4; ++r) {
          float mx = fmaxf(fmaxf(s[0][r], s[1][r]), fmaxf(s[2][r], s[3][r]));
          mx = fmaxf(mx, __shfl_xor(mx, 1));
          mx = fmaxf(mx, __shfl_xor(mx, 2));
          mx = fmaxf(mx, __shfl_xor(mx, 4));
          mx = fmaxf(mx, __shfl_xor(mx, 8));
          float sm = 0.f;
#pragma unroll
          for (int nt = 0; nt < 4; ++nt) {
            float e = __expf(s[nt][r] - mx);
            s[nt][r] = e;
            sm += e;
          }
          sm += __shfl_xor(sm, 1);
          sm += __shfl_xor(sm, 2);
          sm += __shfl_xor(sm, 4);
          sm += __shfl_xor(sm, 8);
          const float iv = 1.0f / sm;
#pragma unroll
          for (int nt = 0; nt < 4; ++nt) s[nt][r] *= iv;
        }
        // P chunk -> wave-private LDS (DS ops in-order within a wave)
#pragma unroll
        for (int nt = 0; nt < 4; ++nt)
#pragma unroll
          for (int r = 0; r < 4; ++r)
            pc[(l4 * 4 + r) * 72 + nt * 16 + l15] = (_Float16)s[nt][r];
        // P A-frags: A[m=q][k=kk]
        hvec8 pf[2];
#pragma unroll
        for (int k2 = 0; k2 < 2; ++k2)
          pf[k2] = *(const hvec8*)&pc[l15 * 72 + k2 * 32 + l4 * 8];
        fvec4 o[2];
#pragma unroll
        for (int nv = 0; nv < 2; ++nv) {
          o[nv] = __builtin_amdgcn_mfma_f32_16x16x32_f16(pf[0], vf[nv][0], fz, 0, 0, 0);
          o[nv] = __builtin_amdgcn_mfma_f32_16x16x32_f16(pf[1], vf[nv][1], o[nv], 0, 0, 0);
        }
#pragma unroll
        for (int nv = 0; nv < 2; ++nv)
#pragma unroll
          for (int r = 0; r < 4; ++r) {
            int row = q4 * 16 + l4 * 4 + r;          // local row in half
            int col = h * 32 + nv * 16 + l15;
            Os[row * 264 + col] = (_Float16)o[nv][r];
          }
      }
    }
    __syncthreads();

    // =============== Stage C half: out rows = Os[64][256] @ proj_w^T + b ====
    {
      const int c0 = wv * 32;  // out-channel slice per wave
      fvec4 po[4][2];
#pragma unroll
      for (int q4 = 0; q4 < 4; ++q4)
#pragma unroll
        for (int nb = 0; nb < 2; ++nb) po[q4][nb] = fz;

      {
        const _Float16* bP = pjwh + ((size_t)(c0 + l15) << 8);
        for (int ks = 0; ks < 8; ++ks) {
          const int k0 = ks * 32 + l4 * 8;
          hvec8 bn0 = *(const hvec8*)(bP + k0);
          hvec8 bn1 = *(const hvec8*)(bP + 16 * 256 + k0);
#pragma unroll
          for (int q4 = 0; q4 < 4; ++q4) {
            hvec8 am = *(const hvec8*)&Os[(q4 * 16 + l15) * 264 + k0];
            po[q4][0] = __builtin_amdgcn_mfma_f32_16x16x32_f16(am, bn0, po[q4][0], 0, 0, 0);
            po[q4][1] = __builtin_amdgcn_mfma_f32_16x16x32_f16(am, bn1, po[q4][1], 0, 0, 0);
          }
        }
      }
      float pb[2];
#pragma unroll
      for (int nb = 0; nb < 2; ++nb) pb[nb] = pjb[c0 + nb * 16 + l15];
      float* ow = out + (size_t)w * (N1 * DIM) + (size_t)half * 64 * DIM;
#pragma unroll
      for (int q4 = 0; q4 < 4; ++q4)
#pragma unroll
        for (int nb = 0; nb < 2; ++nb)
#pragma unroll
          for (int r = 0; r < 4; ++r) {
            int row = q4 * 16 + l4 * 4 + r;
            int col = c0 + nb * 16 + l15;
            __builtin_nontemporal_store(po[q4][nb][r] + pb[nb], &ow[row * 256 + col]);
          }
    }
    if (half == 0) __syncthreads();   // B2 rewrites Os after C1 reads
  }
}

// ---------------------------------------------------------------------------
extern "C" void kernel_launch(void* const* d_in, const int* in_sizes, int n_in,
                              void* d_out, int out_size, void* d_ws, size_t ws_size,
                              hipStream_t stream) {
  (void)in_sizes; (void)n_in; (void)out_size; (void)ws_size;
  const float* embeds = (const float*)d_in[0];  // [1,128,256]
  const float* x      = (const float*)d_in[1];  // [2,256,256,256]
  const float* rpb    = (const float*)d_in[2];  // [225,8]
  const float* kvw    = (const float*)d_in[3];  // [512,256]
  const float* kvb    = (const float*)d_in[4];  // [512]
  const float* pjw    = (const float*)d_in[5];  // [256,256]
  const float* pjb    = (const float*)d_in[6];  // [256]
  float* out = (float*)d_out;                   // [2048,128,256]

  char* ws = (char*)d_ws;                       // 576 KB used
  _Float16* qh    = (_Float16*)(ws);            // 65536 B  : q f16 [8][128][32]
  _Float16* kvwh  = (_Float16*)(ws + 65536);    // 262144 B : kv_w f16
  _Float16* pjwh  = (_Float16*)(ws + 327680);   // 131072 B : proj_w f16
  float*    biasf = (float*)(ws + 458752);      // 131072 B : bias fp32 frag-order

  prep_kernel<<<512, 256, 0, stream>>>(embeds, rpb, kvw, pjw, qh, kvwh, pjwh, biasf);
  attn_kernel<<<NWIN, 512, 0, stream>>>(x, kvb, pjb, qh, kvwh, pjwh, biasf, out);
}